// Round 10
// baseline (226.587 us; speedup 1.0000x reference)
//
#include <hip/hip_runtime.h>

#define NPTS 100000
#define P 64
#define C 128
#define NBLK 1563          // number of 64-point tiles
#define TILES_PER_BLK 2    // grid 782: all blocks co-resident in ONE dispatch round
#define BLK_REC 48         // rec slots per tile (hit points/tile: mean ~7, 48 = ~15 sigma)
#define LIST_CAP 4096      // max hit entries per plane (expected ~180)
#define CNT_STRIDE 16      // u32 stride: one 64B cache line per plane counter
                           // (device atomics serialize PER LINE: r3 1-line=+170us,
                           //  r5 4-line=+65us, r6 64-line=+13us — model confirmed)

typedef __bf16 bf16_t;
typedef __bf16 bf16x4 __attribute__((ext_vector_type(4)));
typedef __bf16 bf16x8 __attribute__((ext_vector_type(8)));
typedef float floatx4 __attribute__((ext_vector_type(4)));

// Workspace layout (bytes):
//   [0,       65536)     W1t bf16 [256][128]   (s1 folded, transposed: [n][k])
//   [65536,  131072)     W2t bf16 [128][256]   (s2 folded, transposed)
//   [131072, 163840)     Wat bf16 [128][128]   (transposed)
//   [163840, 167936)     cnt u32 [64*16] (plane p's counter at cnt[p*16]; 64B/plane)
//   [167936, 1216512)    list u32 [64][LIST_CAP]   entry = (recRow<<1)|sel
//   [1216512, +38.4MB)   rec bf16 [NBLK*BLK_REC][256]  (a[128] | h2[128] per hit point)
//   [39628800, +2MB)     partial f32 [64][16][4][128]
// r9 lesson: bf16 tmp[4] + uint2 pun -> SCRATCH (HBM): +42MB fetch +41MB write,
// main 67->92us. Pack via ext_vector_type (registers) instead.

__global__ __launch_bounds__(256) void prep_kernel(
    const float* __restrict__ W1, const float* __restrict__ s1,
    const float* __restrict__ W2, const float* __restrict__ s2,
    const float* __restrict__ Wa,
    bf16_t* __restrict__ W1t, bf16_t* __restrict__ W2t, bf16_t* __restrict__ Wat,
    unsigned* __restrict__ cnt)
{
  int i0 = blockIdx.x * blockDim.x + threadIdx.x;
  int stride = gridDim.x * blockDim.x;
  for (int i = i0; i < 256 * 128; i += stride) {          // W1t[n][k] = W1[k][n]*s1[n]
    int n = i >> 7, k = i & 127;
    W1t[i] = (bf16_t)(W1[k * 256 + n] * s1[n]);
  }
  for (int i = i0; i < 128 * 256; i += stride) {          // W2t[n][k] = W2[k][n]*s2[n]
    int n = i >> 8, k = i & 255;
    W2t[i] = (bf16_t)(W2[k * 128 + n] * s2[n]);
  }
  for (int i = i0; i < 128 * 128; i += stride) {          // Wat[n][k] = Wa[k][n]
    int n = i >> 7, k = i & 127;
    Wat[i] = (bf16_t)(Wa[k * 128 + n]);
  }
  if (i0 < 64 * CNT_STRIDE) cnt[i0] = 0;                  // zero padded counters
}

// Fused: feature -> h -> h2 -> (logit, a=h2@Wa) -> plane-mask sparse emit.
// 2 tiles per block (grid 782): single dispatch round, no fill/drain dilution.
// Logit phase runs between G2-epilogue and GEMMa (wave-local lgS — no barrier).
__global__ __launch_bounds__(256, 4) void main_kernel(
    const float* __restrict__ feature, const float* __restrict__ xyz,
    const float* __restrict__ b1, const float* __restrict__ b2,
    const float* __restrict__ W3, const float* __restrict__ b3,
    const float* __restrict__ ctr, const float* __restrict__ nrm,
    const float* __restrict__ pmn, const float* __restrict__ pmx,
    const bf16_t* __restrict__ W1t, const bf16_t* __restrict__ W2t,
    const bf16_t* __restrict__ Wat,
    unsigned* __restrict__ cnt, unsigned* __restrict__ list,
    bf16_t* __restrict__ rec, float* __restrict__ out_logit)
{
  // LDS: A1 bf16[64][136] (feature tile; later h2)          @0      17408
  //      Hh bf16[64][136] (h-half; later aB = a output)     @17408  17408
  //      w3S f32[128] @34816 | xyzS f32[192] @35328 | lgS f32[64] @36096 | blkCnt @36352
  __shared__ __align__(16) char smem[36368];
  bf16_t* A1   = (bf16_t*)smem;
  bf16_t* Hh   = (bf16_t*)(smem + 17408);
  bf16_t* aB   = (bf16_t*)(smem + 17408);          // overlays Hh after GEMM2
  float*  w3S  = (float*)(smem + 34816);
  float*  xyzS = (float*)(smem + 35328);
  float*  lgS  = (float*)(smem + 36096);
  unsigned* blkCnt = (unsigned*)(smem + 36352);

  const int tid  = threadIdx.x;
  const int wave = tid >> 6, lane = tid & 63;
  const int quad = lane >> 4, l16 = lane & 15;

  if (tid < 128) w3S[tid] = W3[tid];               // once per block

  const floatx4 zero4 = {0.f, 0.f, 0.f, 0.f};

  for (int t = 0; t < TILES_PER_BLK; ++t) {
    const int tIdx = blockIdx.x * TILES_PER_BLK + t;
    if (tIdx < NBLK) {
      const int m0 = tIdx * 64;

      // ---- tile prologue: blkCnt, xyz tile, feature tile ----
      if (tid == 0) *blkCnt = 0;
      if (tid < 192) {
        int gi = m0 * 3 + tid;
        xyzS[tid] = (gi < NPTS * 3) ? xyz[gi] : 0.f;
      }
      for (int i = tid; i < 64 * 32; i += 256) {   // 32 float4 per row
        int r = i >> 5, c4 = i & 31;
        float4 v = make_float4(0.f, 0.f, 0.f, 0.f);
        if (m0 + r < NPTS) v = *(const float4*)(feature + (size_t)(m0 + r) * C + c4 * 4);
        // ext_vector pack: stays in VGPRs (r9's stack-array pun went to scratch)
        bf16x4 tmp = {(bf16_t)v.x, (bf16_t)v.y, (bf16_t)v.z, (bf16_t)v.w};
        *(bf16x4*)(A1 + r * 136 + c4 * 4) = tmp;   // single ds_write_b64
      }
      __syncthreads();

      // ---- GEMM1+GEMM2 fused over two 128-col halves of h ----
      floatx4 acc2[4][2];
#pragma unroll
      for (int mt = 0; mt < 4; ++mt) { acc2[mt][0] = zero4; acc2[mt][1] = zero4; }

#pragma unroll
      for (int half = 0; half < 2; ++half) {
        floatx4 acc1[4][2];
#pragma unroll
        for (int mt = 0; mt < 4; ++mt) { acc1[mt][0] = zero4; acc1[mt][1] = zero4; }
#pragma unroll
        for (int kt = 0; kt < 4; ++kt) {
          bf16x8 af[4], bfr[2];
#pragma unroll
          for (int mt = 0; mt < 4; ++mt)
            af[mt] = *(const bf16x8*)(A1 + (mt * 16 + l16) * 136 + kt * 32 + quad * 8);
#pragma unroll
          for (int nt = 0; nt < 2; ++nt)
            bfr[nt] = *(const bf16x8*)(W1t + (size_t)(half * 128 + wave * 32 + nt * 16 + l16) * 128 + kt * 32 + quad * 8);
#pragma unroll
          for (int mt = 0; mt < 4; ++mt)
#pragma unroll
            for (int nt = 0; nt < 2; ++nt)
              acc1[mt][nt] = __builtin_amdgcn_mfma_f32_16x16x32_bf16(af[mt], bfr[nt], acc1[mt][nt], 0, 0, 0);
        }
#pragma unroll
        for (int nt = 0; nt < 2; ++nt) {
          int hcol = wave * 32 + nt * 16 + l16;
          float bias = b1[half * 128 + hcol];
#pragma unroll
          for (int mt = 0; mt < 4; ++mt)
#pragma unroll
            for (int r = 0; r < 4; ++r) {
              float hv = fmaxf(acc1[mt][nt][r] + bias, 0.f);
              Hh[(mt * 16 + quad * 4 + r) * 136 + hcol] = (bf16_t)hv;
            }
        }
        __syncthreads();     // Hh half ready

#pragma unroll
        for (int kt = 0; kt < 4; ++kt) {
          bf16x8 af[4], bfr[2];
#pragma unroll
          for (int mt = 0; mt < 4; ++mt)
            af[mt] = *(const bf16x8*)(Hh + (mt * 16 + l16) * 136 + kt * 32 + quad * 8);
#pragma unroll
          for (int nt = 0; nt < 2; ++nt)
            bfr[nt] = *(const bf16x8*)(W2t + (size_t)(wave * 32 + nt * 16 + l16) * 256 + half * 128 + kt * 32 + quad * 8);
#pragma unroll
          for (int mt = 0; mt < 4; ++mt)
#pragma unroll
            for (int nt = 0; nt < 2; ++nt)
              acc2[mt][nt] = __builtin_amdgcn_mfma_f32_16x16x32_bf16(af[mt], bfr[nt], acc2[mt][nt], 0, 0, 0);
        }
        __syncthreads();     // Hh reads done (next half overwrites)
      }

      // ---- GEMM2 epilogue: h2 -> bf16 into A1 (feature no longer needed) ----
#pragma unroll
      for (int nt = 0; nt < 2; ++nt) {
        int col = wave * 32 + nt * 16 + l16;
        float bias = b2[col];
#pragma unroll
        for (int mt = 0; mt < 4; ++mt)
#pragma unroll
          for (int r = 0; r < 4; ++r) {
            float hv = fmaxf(acc2[mt][nt][r] + bias, 0.f);
            A1[(mt * 16 + quad * 4 + r) * 136 + col] = (bf16_t)hv;
          }
      }
      __syncthreads();   // A1 now h2, visible to all

      // ---- logit (wave-local: thread pt*4+g and lgS[pt] reader share a wave) ----
      {
        const int m = tid >> 2, g = tid & 3, c0g = g * 32;
        const int mg = m0 + m;
        const bf16x8* src = (const bf16x8*)(A1 + m * 136 + c0g);  // 16B-aligned
        float lsum = 0.f;
#pragma unroll
        for (int v8 = 0; v8 < 4; ++v8) {
          bf16x8 hv = src[v8];
#pragma unroll
          for (int e = 0; e < 8; ++e)
            lsum += (float)hv[e] * w3S[c0g + v8 * 8 + e];
        }
        lsum += __shfl_xor(lsum, 1);
        lsum += __shfl_xor(lsum, 2);
        if (g == 0) {
          float lg = lsum + b3[0];
          lgS[m] = lg;
          if (mg < NPTS) out_logit[mg] = lg;
        }
      }
      // no barrier: lgS consumed wave-locally (and GEMMa's barrier precedes mask)

      // ---- GEMMa: a[64][128] = h2 @ Wa -> bf16 into aB (overlays Hh) ----
      {
        floatx4 acca[4][2];
#pragma unroll
        for (int mt = 0; mt < 4; ++mt) { acca[mt][0] = zero4; acca[mt][1] = zero4; }
#pragma unroll
        for (int kt = 0; kt < 4; ++kt) {
          bf16x8 af[4], bfr[2];
#pragma unroll
          for (int mt = 0; mt < 4; ++mt)
            af[mt] = *(const bf16x8*)(A1 + (mt * 16 + l16) * 136 + kt * 32 + quad * 8);
#pragma unroll
          for (int nt = 0; nt < 2; ++nt)
            bfr[nt] = *(const bf16x8*)(Wat + (size_t)(wave * 32 + nt * 16 + l16) * 128 + kt * 32 + quad * 8);
#pragma unroll
          for (int mt = 0; mt < 4; ++mt)
#pragma unroll
            for (int nt = 0; nt < 2; ++nt)
              acca[mt][nt] = __builtin_amdgcn_mfma_f32_16x16x32_bf16(af[mt], bfr[nt], acca[mt][nt], 0, 0, 0);
        }
#pragma unroll
        for (int nt = 0; nt < 2; ++nt) {
          int col = wave * 32 + nt * 16 + l16;
#pragma unroll
          for (int mt = 0; mt < 4; ++mt)
#pragma unroll
            for (int r = 0; r < 4; ++r)
              aB[(mt * 16 + quad * 4 + r) * 136 + col] = (bf16_t)acca[mt][nt][r];
        }
      }
      __syncthreads();   // aB visible to all; lgS already wave-visible

      // ---- fused mask phase: lane = plane (P==64==wave width); sparse emit ----
      {
        const float nx = nrm[lane * 3], ny = nrm[lane * 3 + 1], nz = nrm[lane * 3 + 2];
        const float offsP = ctr[lane * 3] * nx + ctr[lane * 3 + 1] * ny + ctr[lane * 3 + 2] * nz;
        const float mnx = pmn[lane * 3], mny = pmn[lane * 3 + 1];
        const float mxx = pmx[lane * 3], mxy = pmx[lane * 3 + 1];

        for (int s = 0; s < 16; ++s) {             // wave w owns points [w*16,+16)
          const int pt = wave * 16 + s;
          const bool valid = (m0 + pt) < NPTS;
          const float x = xyzS[pt * 3], y = xyzS[pt * 3 + 1], z = xyzS[pt * 3 + 2];
          const float proj = x * nx + y * ny + z * nz;
          const bool hit = valid && (fabsf(proj - offsP) < 0.1f) &&
                           (x >= mnx) && (x < mxx) && (y >= mny) && (y < mxy);
          unsigned long long mball = __ballot(hit);
          if (!mball) continue;                    // wave-uniform skip

          unsigned slot = 0;                       // block-local rec slot (LDS atomic)
          if (lane == 0) slot = atomicAdd(blkCnt, 1u);
          slot = (unsigned)__shfl((int)slot, 0);
          if (slot >= BLK_REC) continue;           // ~15-sigma overflow guard

          const unsigned ridx = (unsigned)tIdx * BLK_REC + slot;
          const int sel = (lgS[pt] > 0.f) ? 0 : 1; // on=0, off=1
          const unsigned ap = ((const unsigned*)(aB + pt * 136))[lane];
          const unsigned hp = ((const unsigned*)(A1 + pt * 136))[lane];
          unsigned* dst = (unsigned*)(rec + (size_t)ridx * 256);
          dst[lane]      = ap;                     // a row  (bf16 pairs)
          dst[64 + lane] = hp;                     // h2 row
          if (hit) {                               // hitting lane -> its plane's list
            unsigned idx = atomicAdd(&cnt[lane * CNT_STRIDE], 1u);  // private 64B line
            if (idx < LIST_CAP)
              list[lane * LIST_CAP + idx] = (ridx << 1) | (unsigned)sel;
          }
        }
      }
      __syncthreads();   // end of tile: A1/aB/xyzS/lgS/blkCnt free for next tile
    }
  }
}

// Gather: 64 planes x 16 chunks (1024 blocks — r7's 64-block fusion was
// latency-dead at 1 wave/CU). Register accum, LDS reduce, write partials.
__global__ __launch_bounds__(256) void pool2_kernel(
    const unsigned* __restrict__ cnt, const unsigned* __restrict__ list,
    const bf16_t* __restrict__ rec, float* __restrict__ partial)
{
  const int plane = blockIdx.x >> 4;
  const int chunk = blockIdx.x & 15;
  const int tid = threadIdx.x, wave = tid >> 6, lane = tid & 63;

  __shared__ float accS[4][128];   // num_on, den_on, num_off, den_off
  for (int i = tid; i < 512; i += 256) ((float*)accS)[i] = 0.f;
  __syncthreads();

  unsigned n = cnt[plane * CNT_STRIDE];
  if (n > LIST_CAP) n = LIST_CAP;
  const unsigned* lp = list + plane * LIST_CAP;

  float nOn0 = 0, nOn1 = 0, dOn0 = 0, dOn1 = 0;
  float nOf0 = 0, nOf1 = 0, dOf0 = 0, dOf1 = 0;

  for (unsigned e = (unsigned)(chunk * 4 + wave); e < n; e += 64) {
    const unsigned ent = lp[e];                     // wave-uniform load
    const unsigned row = ent >> 1;
    const unsigned* r32 = (const unsigned*)(rec + (size_t)row * 256);
    const unsigned ap = r32[lane];
    const unsigned hp = r32[64 + lane];
    const float a0 = __uint_as_float(ap << 16);
    const float a1 = __uint_as_float(ap & 0xffff0000u);
    const float h0 = __uint_as_float(hp << 16);
    const float h1 = __uint_as_float(hp & 0xffff0000u);
    const float e0 = __expf(a0), e1 = __expf(a1);
    if (!(ent & 1)) { nOn0 += e0 * h0; nOn1 += e1 * h1; dOn0 += e0; dOn1 += e1; }
    else            { nOf0 += e0 * h0; nOf1 += e1 * h1; dOf0 += e0; dOf1 += e1; }
  }

  atomicAdd(&accS[0][lane * 2],     nOn0);
  atomicAdd(&accS[0][lane * 2 + 1], nOn1);
  atomicAdd(&accS[1][lane * 2],     dOn0);
  atomicAdd(&accS[1][lane * 2 + 1], dOn1);
  atomicAdd(&accS[2][lane * 2],     nOf0);
  atomicAdd(&accS[2][lane * 2 + 1], nOf1);
  atomicAdd(&accS[3][lane * 2],     dOf0);
  atomicAdd(&accS[3][lane * 2 + 1], dOf1);
  __syncthreads();

  float* dst = partial + (size_t)blockIdx.x * 512;
  for (int i = tid; i < 512; i += 256) dst[i] = ((float*)accS)[i];
}

// Finalize: sum partials over chunks, agg = num/(den+1e-9), relu(agg@Wm+bm), ori.
__global__ __launch_bounds__(128) void finalize_kernel(
    const float* __restrict__ partial,
    const float* __restrict__ Wm, const float* __restrict__ bm,
    const float* __restrict__ ctr, const float* __restrict__ nrm,
    const float* __restrict__ pmn, const float* __restrict__ pmx,
    float* __restrict__ out)
{
  int sel = blockIdx.x >> 6, p = blockIdx.x & 63;
  int j = threadIdx.x;
  float num = 0.f, den = 0.f;
  const float* bp = partial + (size_t)p * 16 * 512 + sel * 2 * 128;
#pragma unroll
  for (int k = 0; k < 16; ++k) {
    num += bp[k * 512 + j];
    den += bp[k * 512 + 128 + j];
  }
  __shared__ float aggS[128];
  aggS[j] = num / (den + 1e-9f);
  __syncthreads();
  float s = bm[j];
#pragma unroll 4
  for (int c = 0; c < C; ++c) s += aggS[c] * Wm[c * C + j];
  s = fmaxf(s, 0.f);
  float* dst = out + NPTS + sel * (P * 140) + p * 140;
  dst[j] = s;
  if (j < 12) {
    float v;
    if (j < 3)      v = ctr[p * 3 + j];
    else if (j < 6) v = nrm[p * 3 + j - 3];
    else if (j < 9) v = pmn[p * 3 + j - 6];
    else            v = pmx[p * 3 + j - 9];
    dst[C + j] = v;
  }
}

extern "C" void kernel_launch(void* const* d_in, const int* in_sizes, int n_in,
                              void* d_out, int out_size, void* d_ws, size_t ws_size,
                              hipStream_t stream)
{
  const float* feature = (const float*)d_in[0];
  const float* xyz     = (const float*)d_in[1];
  const float* ctr     = (const float*)d_in[2];
  const float* nrm     = (const float*)d_in[3];
  const float* pmn     = (const float*)d_in[4];
  const float* pmx     = (const float*)d_in[5];
  const float* W1      = (const float*)d_in[6];
  const float* s1      = (const float*)d_in[7];
  const float* b1      = (const float*)d_in[8];
  const float* W2      = (const float*)d_in[9];
  const float* s2      = (const float*)d_in[10];
  const float* b2      = (const float*)d_in[11];
  const float* W3      = (const float*)d_in[12];
  const float* b3      = (const float*)d_in[13];
  const float* Wa      = (const float*)d_in[14];
  const float* Wm      = (const float*)d_in[15];
  const float* bm      = (const float*)d_in[16];
  float* out = (float*)d_out;

  char* ws = (char*)d_ws;
  bf16_t*   W1t  = (bf16_t*)(ws);
  bf16_t*   W2t  = (bf16_t*)(ws + 65536);
  bf16_t*   Wat  = (bf16_t*)(ws + 131072);
  unsigned* cnt  = (unsigned*)(ws + 163840);                      // 64*16 u32 = 4KB
  unsigned* list = (unsigned*)(ws + 167936);                      // 64*4096 u32 = 1MB
  bf16_t*   rec  = (bf16_t*)(ws + 1216512);                       // NBLK*48*512B = 38.4MB
  float* partial = (float*)(ws + 1216512 + (size_t)NBLK * BLK_REC * 512); // 2MB

  prep_kernel<<<64, 256, 0, stream>>>(W1, s1, W2, s2, Wa, W1t, W2t, Wat, cnt);
  main_kernel<<<(NBLK + TILES_PER_BLK - 1) / TILES_PER_BLK, 256, 0, stream>>>(
      feature, xyz, b1, b2, W3, b3, ctr, nrm, pmn, pmx,
      W1t, W2t, Wat, cnt, list, rec, out);
  pool2_kernel<<<64 * 16, 256, 0, stream>>>(cnt, list, rec, partial);
  finalize_kernel<<<128, 128, 0, stream>>>(partial, Wm, bm, ctr, nrm, pmn, pmx, out);
}

// Round 11
// 191.042 us; speedup vs baseline: 1.1861x; 1.1861x over previous
//
#include <hip/hip_runtime.h>

#define NPTS 100000
#define P 64
#define C 128
#define NBLK 1563          // (NPTS+63)/64
#define BLK_REC 48         // rec slots per block (hit points/block: mean ~7, 48 = ~15 sigma)
#define LIST_CAP 4096      // max hit entries per plane (expected ~180)
#define CNT_STRIDE 16      // u32 stride: one 64B cache line per plane counter
                           // (device atomics serialize PER LINE: r3 1-line=+170us,
                           //  r5 4-line=+65us, r6 64-line=+13us — model confirmed)
// r9/r10 lesson: wrapping the kernel body in a 2-tile loop (grid 782) induced
// ~41MB/dispatch of spill round-trip traffic (VGPR 56->64, FETCH+42MB, WRITE+41MB),
// invariant to how the staging pack was written. Keep ONE tile per block.

typedef __bf16 bf16_t;
typedef __bf16 bf16x8 __attribute__((ext_vector_type(8)));
typedef float floatx4 __attribute__((ext_vector_type(4)));

// Workspace layout (bytes):
//   [0,       65536)     W1t bf16 [256][128]   (s1 folded, transposed: [n][k])
//   [65536,  131072)     W2t bf16 [128][256]   (s2 folded, transposed)
//   [131072, 163840)     Wat bf16 [128][128]   (transposed)
//   [163840, 167936)     cnt u32 [64*16] (plane p's counter at cnt[p*16]; 64B/plane)
//   [167936, 1216512)    list u32 [64][LIST_CAP]   entry = (recRow<<1)|sel
//   [1216512, +38.4MB)   rec bf16 [NBLK*BLK_REC][256]  (a[128] | h2[128] per hit point)
//   [39628800, +2MB)     partial f32 [64][16][4][128]

__global__ __launch_bounds__(256) void prep_kernel(
    const float* __restrict__ W1, const float* __restrict__ s1,
    const float* __restrict__ W2, const float* __restrict__ s2,
    const float* __restrict__ Wa,
    bf16_t* __restrict__ W1t, bf16_t* __restrict__ W2t, bf16_t* __restrict__ Wat,
    unsigned* __restrict__ cnt)
{
  int i0 = blockIdx.x * blockDim.x + threadIdx.x;
  int stride = gridDim.x * blockDim.x;
  for (int i = i0; i < 256 * 128; i += stride) {          // W1t[n][k] = W1[k][n]*s1[n]
    int n = i >> 7, k = i & 127;
    W1t[i] = (bf16_t)(W1[k * 256 + n] * s1[n]);
  }
  for (int i = i0; i < 128 * 256; i += stride) {          // W2t[n][k] = W2[k][n]*s2[n]
    int n = i >> 8, k = i & 255;
    W2t[i] = (bf16_t)(W2[k * 128 + n] * s2[n]);
  }
  for (int i = i0; i < 128 * 128; i += stride) {          // Wat[n][k] = Wa[k][n]
    int n = i >> 7, k = i & 127;
    Wat[i] = (bf16_t)(Wa[k * 128 + n]);
  }
  if (i0 < 64 * CNT_STRIDE) cnt[i0] = 0;                  // zero padded counters
}

// Fused: feature -> h -> h2 -> (logit, a=h2@Wa) -> plane-mask sparse emit.
// LDS 36.4KB: h computed in TWO 128-col halves staged in Hh[64][136], each
// immediately consumed into the persistent GEMM2 accumulator.
__global__ __launch_bounds__(256, 4) void main_kernel(
    const float* __restrict__ feature, const float* __restrict__ xyz,
    const float* __restrict__ b1, const float* __restrict__ b2,
    const float* __restrict__ W3, const float* __restrict__ b3,
    const float* __restrict__ ctr, const float* __restrict__ nrm,
    const float* __restrict__ pmn, const float* __restrict__ pmx,
    const bf16_t* __restrict__ W1t, const bf16_t* __restrict__ W2t,
    const bf16_t* __restrict__ Wat,
    unsigned* __restrict__ cnt, unsigned* __restrict__ list,
    bf16_t* __restrict__ rec, float* __restrict__ out_logit)
{
  // LDS: A1 bf16[64][136] (feature tile; later h2)          @0      17408
  //      Hh bf16[64][136] (h-half; later aB = a output)     @17408  17408
  //      w3S f32[128] @34816 | xyzS f32[192] @35328 | lgS f32[64] @36096 | blkCnt @36352
  __shared__ __align__(16) char smem[36368];
  bf16_t* A1   = (bf16_t*)smem;
  bf16_t* Hh   = (bf16_t*)(smem + 17408);
  bf16_t* aB   = (bf16_t*)(smem + 17408);          // overlays Hh after GEMM2
  float*  w3S  = (float*)(smem + 34816);
  float*  xyzS = (float*)(smem + 35328);
  float*  lgS  = (float*)(smem + 36096);
  unsigned* blkCnt = (unsigned*)(smem + 36352);

  const int tid  = threadIdx.x;
  const int wave = tid >> 6, lane = tid & 63;
  const int quad = lane >> 4, l16 = lane & 15;
  const int m0 = blockIdx.x * 64;

  if (tid < 128) w3S[tid] = W3[tid];
  if (tid < 192) {                                  // stage xyz tile (64 pts x 3)
    int gi = m0 * 3 + tid;
    xyzS[tid] = (gi < NPTS * 3) ? xyz[gi] : 0.f;
  }
  if (tid == 0) *blkCnt = 0;

  // ---- stage feature tile (fp32 -> bf16) ----
  for (int i = tid; i < 64 * 32; i += 256) {   // 32 float4 per row
    int r = i >> 5, c4 = i & 31;
    float4 v = make_float4(0.f, 0.f, 0.f, 0.f);
    if (m0 + r < NPTS) v = *(const float4*)(feature + (size_t)(m0 + r) * C + c4 * 4);
    bf16_t* dst = A1 + r * 136 + c4 * 4;
    dst[0] = (bf16_t)v.x; dst[1] = (bf16_t)v.y; dst[2] = (bf16_t)v.z; dst[3] = (bf16_t)v.w;
  }
  __syncthreads();

  const floatx4 zero4 = {0.f, 0.f, 0.f, 0.f};

  // ---- GEMM1+GEMM2 fused over two 128-col halves of h ----
  // acc2 accumulates h2 = relu(h @ W2' + b2) across both halves' k-ranges.
  floatx4 acc2[4][2];
#pragma unroll
  for (int mt = 0; mt < 4; ++mt) { acc2[mt][0] = zero4; acc2[mt][1] = zero4; }

#pragma unroll
  for (int half = 0; half < 2; ++half) {
    // GEMM1 half: h[:, half*128 + (0..128)] = relu(A1 @ W1t-half + b1)
    floatx4 acc1[4][2];
#pragma unroll
    for (int mt = 0; mt < 4; ++mt) { acc1[mt][0] = zero4; acc1[mt][1] = zero4; }
#pragma unroll
    for (int kt = 0; kt < 4; ++kt) {
      bf16x8 af[4], bfr[2];
#pragma unroll
      for (int mt = 0; mt < 4; ++mt)
        af[mt] = *(const bf16x8*)(A1 + (mt * 16 + l16) * 136 + kt * 32 + quad * 8);
#pragma unroll
      for (int nt = 0; nt < 2; ++nt)
        bfr[nt] = *(const bf16x8*)(W1t + (size_t)(half * 128 + wave * 32 + nt * 16 + l16) * 128 + kt * 32 + quad * 8);
#pragma unroll
      for (int mt = 0; mt < 4; ++mt)
#pragma unroll
        for (int nt = 0; nt < 2; ++nt)
          acc1[mt][nt] = __builtin_amdgcn_mfma_f32_16x16x32_bf16(af[mt], bfr[nt], acc1[mt][nt], 0, 0, 0);
    }
#pragma unroll
    for (int nt = 0; nt < 2; ++nt) {
      int hcol = wave * 32 + nt * 16 + l16;
      float bias = b1[half * 128 + hcol];
#pragma unroll
      for (int mt = 0; mt < 4; ++mt)
#pragma unroll
        for (int r = 0; r < 4; ++r) {
          float hv = fmaxf(acc1[mt][nt][r] + bias, 0.f);
          Hh[(mt * 16 + quad * 4 + r) * 136 + hcol] = (bf16_t)hv;
        }
    }
    __syncthreads();     // Hh half ready

    // GEMM2 partial: accumulate over this half's k-range
#pragma unroll
    for (int kt = 0; kt < 4; ++kt) {
      bf16x8 af[4], bfr[2];
#pragma unroll
      for (int mt = 0; mt < 4; ++mt)
        af[mt] = *(const bf16x8*)(Hh + (mt * 16 + l16) * 136 + kt * 32 + quad * 8);
#pragma unroll
      for (int nt = 0; nt < 2; ++nt)
        bfr[nt] = *(const bf16x8*)(W2t + (size_t)(wave * 32 + nt * 16 + l16) * 256 + half * 128 + kt * 32 + quad * 8);
#pragma unroll
      for (int mt = 0; mt < 4; ++mt)
#pragma unroll
        for (int nt = 0; nt < 2; ++nt)
          acc2[mt][nt] = __builtin_amdgcn_mfma_f32_16x16x32_bf16(af[mt], bfr[nt], acc2[mt][nt], 0, 0, 0);
    }
    __syncthreads();     // Hh reads done (next half overwrites)
  }

  // ---- GEMM2 epilogue: h2 -> bf16 into A1 (feature no longer needed) ----
#pragma unroll
  for (int nt = 0; nt < 2; ++nt) {
    int col = wave * 32 + nt * 16 + l16;
    float bias = b2[col];
#pragma unroll
    for (int mt = 0; mt < 4; ++mt)
#pragma unroll
      for (int r = 0; r < 4; ++r) {
        float hv = fmaxf(acc2[mt][nt][r] + bias, 0.f);
        A1[(mt * 16 + quad * 4 + r) * 136 + col] = (bf16_t)hv;
      }
  }
  __syncthreads();   // A1 now h2, visible to all

  // ---- GEMMa: a[64][128] = h2 @ Wa -> bf16 into aB (overlays Hh) ----
  {
    floatx4 acca[4][2];
#pragma unroll
    for (int mt = 0; mt < 4; ++mt) { acca[mt][0] = zero4; acca[mt][1] = zero4; }
#pragma unroll
    for (int kt = 0; kt < 4; ++kt) {
      bf16x8 af[4], bfr[2];
#pragma unroll
      for (int mt = 0; mt < 4; ++mt)
        af[mt] = *(const bf16x8*)(A1 + (mt * 16 + l16) * 136 + kt * 32 + quad * 8);
#pragma unroll
      for (int nt = 0; nt < 2; ++nt)
        bfr[nt] = *(const bf16x8*)(Wat + (size_t)(wave * 32 + nt * 16 + l16) * 128 + kt * 32 + quad * 8);
#pragma unroll
      for (int mt = 0; mt < 4; ++mt)
#pragma unroll
        for (int nt = 0; nt < 2; ++nt)
          acca[mt][nt] = __builtin_amdgcn_mfma_f32_16x16x32_bf16(af[mt], bfr[nt], acca[mt][nt], 0, 0, 0);
    }
#pragma unroll
    for (int nt = 0; nt < 2; ++nt) {
      int col = wave * 32 + nt * 16 + l16;
#pragma unroll
      for (int mt = 0; mt < 4; ++mt)
#pragma unroll
        for (int r = 0; r < 4; ++r)
          aB[(mt * 16 + quad * 4 + r) * 136 + col] = (bf16_t)acca[mt][nt][r];
    }
  }
  __syncthreads();

  // ---- logit: 4 threads/point, 32 channels each; also stash logit in LDS ----
  {
    const int m = tid >> 2, g = tid & 3, c0g = g * 32;
    const int mg = m0 + m;
    float lsum = 0.f;
#pragma unroll 8
    for (int c = 0; c < 32; ++c)
      lsum += (float)A1[m * 136 + c0g + c] * w3S[c0g + c];
    lsum += __shfl_xor(lsum, 1);
    lsum += __shfl_xor(lsum, 2);
    if (g == 0) {
      float lg = lsum + b3[0];
      lgS[m] = lg;
      if (mg < NPTS) out_logit[mg] = lg;
    }
  }
  __syncthreads();   // lgS visible; A1 (h2) and aB (a) still live

  // ---- fused mask phase: lane = plane (P==64==wave width); sparse emit ----
  {
    const float nx = nrm[lane * 3], ny = nrm[lane * 3 + 1], nz = nrm[lane * 3 + 2];
    const float offsP = ctr[lane * 3] * nx + ctr[lane * 3 + 1] * ny + ctr[lane * 3 + 2] * nz;
    const float mnx = pmn[lane * 3], mny = pmn[lane * 3 + 1];
    const float mxx = pmx[lane * 3], mxy = pmx[lane * 3 + 1];

    // wave w owns points [w*16, w*16+16)
    for (int s = 0; s < 16; ++s) {
      const int pt = wave * 16 + s;
      const bool valid = (m0 + pt) < NPTS;
      const float x = xyzS[pt * 3], y = xyzS[pt * 3 + 1], z = xyzS[pt * 3 + 2];
      const float proj = x * nx + y * ny + z * nz;
      const bool hit = valid && (fabsf(proj - offsP) < 0.1f) &&
                       (x >= mnx) && (x < mxx) && (y >= mny) && (y < mxy);
      unsigned long long mball = __ballot(hit);
      if (!mball) continue;                         // wave-uniform skip

      unsigned slot = 0;                            // block-local rec slot (LDS atomic)
      if (lane == 0) slot = atomicAdd(blkCnt, 1u);
      slot = (unsigned)__shfl((int)slot, 0);
      if (slot >= BLK_REC) continue;                // ~15-sigma overflow guard

      const unsigned ridx = (unsigned)blockIdx.x * BLK_REC + slot;
      const int sel = (lgS[pt] > 0.f) ? 0 : 1;      // on=0, off=1
      const unsigned ap = ((const unsigned*)(aB + pt * 136))[lane];
      const unsigned hp = ((const unsigned*)(A1 + pt * 136))[lane];
      unsigned* dst = (unsigned*)(rec + (size_t)ridx * 256);
      dst[lane]      = ap;                           // a row  (bf16 pairs)
      dst[64 + lane] = hp;                           // h2 row
      if (hit) {                                     // hitting lane -> its plane's list
        unsigned idx = atomicAdd(&cnt[lane * CNT_STRIDE], 1u);  // private 64B line
        if (idx < LIST_CAP)
          list[lane * LIST_CAP + idx] = (ridx << 1) | (unsigned)sel;
      }
    }
  }
}

// Gather: 64 planes x 16 chunks (1024 blocks — r7's 64-block fusion was
// latency-dead at 1 wave/CU). Register accum, LDS reduce, write partials.
__global__ __launch_bounds__(256) void pool2_kernel(
    const unsigned* __restrict__ cnt, const unsigned* __restrict__ list,
    const bf16_t* __restrict__ rec, float* __restrict__ partial)
{
  const int plane = blockIdx.x >> 4;
  const int chunk = blockIdx.x & 15;
  const int tid = threadIdx.x, wave = tid >> 6, lane = tid & 63;

  __shared__ float accS[4][128];   // num_on, den_on, num_off, den_off
  for (int i = tid; i < 512; i += 256) ((float*)accS)[i] = 0.f;
  __syncthreads();

  unsigned n = cnt[plane * CNT_STRIDE];
  if (n > LIST_CAP) n = LIST_CAP;
  const unsigned* lp = list + plane * LIST_CAP;

  float nOn0 = 0, nOn1 = 0, dOn0 = 0, dOn1 = 0;
  float nOf0 = 0, nOf1 = 0, dOf0 = 0, dOf1 = 0;

  for (unsigned e = (unsigned)(chunk * 4 + wave); e < n; e += 64) {
    const unsigned ent = lp[e];                     // wave-uniform load
    const unsigned row = ent >> 1;
    const unsigned* r32 = (const unsigned*)(rec + (size_t)row * 256);
    const unsigned ap = r32[lane];
    const unsigned hp = r32[64 + lane];
    const float a0 = __uint_as_float(ap << 16);
    const float a1 = __uint_as_float(ap & 0xffff0000u);
    const float h0 = __uint_as_float(hp << 16);
    const float h1 = __uint_as_float(hp & 0xffff0000u);
    const float e0 = __expf(a0), e1 = __expf(a1);
    if (!(ent & 1)) { nOn0 += e0 * h0; nOn1 += e1 * h1; dOn0 += e0; dOn1 += e1; }
    else            { nOf0 += e0 * h0; nOf1 += e1 * h1; dOf0 += e0; dOf1 += e1; }
  }

  atomicAdd(&accS[0][lane * 2],     nOn0);
  atomicAdd(&accS[0][lane * 2 + 1], nOn1);
  atomicAdd(&accS[1][lane * 2],     dOn0);
  atomicAdd(&accS[1][lane * 2 + 1], dOn1);
  atomicAdd(&accS[2][lane * 2],     nOf0);
  atomicAdd(&accS[2][lane * 2 + 1], nOf1);
  atomicAdd(&accS[3][lane * 2],     dOf0);
  atomicAdd(&accS[3][lane * 2 + 1], dOf1);
  __syncthreads();

  float* dst = partial + (size_t)blockIdx.x * 512;
  for (int i = tid; i < 512; i += 256) dst[i] = ((float*)accS)[i];
}

// Finalize: sum partials over chunks, agg = num/(den+1e-9), relu(agg@Wm+bm), ori.
__global__ __launch_bounds__(128) void finalize_kernel(
    const float* __restrict__ partial,
    const float* __restrict__ Wm, const float* __restrict__ bm,
    const float* __restrict__ ctr, const float* __restrict__ nrm,
    const float* __restrict__ pmn, const float* __restrict__ pmx,
    float* __restrict__ out)
{
  int sel = blockIdx.x >> 6, p = blockIdx.x & 63;
  int j = threadIdx.x;
  float num = 0.f, den = 0.f;
  const float* bp = partial + (size_t)p * 16 * 512 + sel * 2 * 128;
#pragma unroll
  for (int k = 0; k < 16; ++k) {
    num += bp[k * 512 + j];
    den += bp[k * 512 + 128 + j];
  }
  __shared__ float aggS[128];
  aggS[j] = num / (den + 1e-9f);
  __syncthreads();
  float s = bm[j];
#pragma unroll 4
  for (int c = 0; c < C; ++c) s += aggS[c] * Wm[c * C + j];
  s = fmaxf(s, 0.f);
  float* dst = out + NPTS + sel * (P * 140) + p * 140;
  dst[j] = s;
  if (j < 12) {
    float v;
    if (j < 3)      v = ctr[p * 3 + j];
    else if (j < 6) v = nrm[p * 3 + j - 3];
    else if (j < 9) v = pmn[p * 3 + j - 6];
    else            v = pmx[p * 3 + j - 9];
    dst[C + j] = v;
  }
}

extern "C" void kernel_launch(void* const* d_in, const int* in_sizes, int n_in,
                              void* d_out, int out_size, void* d_ws, size_t ws_size,
                              hipStream_t stream)
{
  const float* feature = (const float*)d_in[0];
  const float* xyz     = (const float*)d_in[1];
  const float* ctr     = (const float*)d_in[2];
  const float* nrm     = (const float*)d_in[3];
  const float* pmn     = (const float*)d_in[4];
  const float* pmx     = (const float*)d_in[5];
  const float* W1      = (const float*)d_in[6];
  const float* s1      = (const float*)d_in[7];
  const float* b1      = (const float*)d_in[8];
  const float* W2      = (const float*)d_in[9];
  const float* s2      = (const float*)d_in[10];
  const float* b2      = (const float*)d_in[11];
  const float* W3      = (const float*)d_in[12];
  const float* b3      = (const float*)d_in[13];
  const float* Wa      = (const float*)d_in[14];
  const float* Wm      = (const float*)d_in[15];
  const float* bm      = (const float*)d_in[16];
  float* out = (float*)d_out;

  char* ws = (char*)d_ws;
  bf16_t*   W1t  = (bf16_t*)(ws);
  bf16_t*   W2t  = (bf16_t*)(ws + 65536);
  bf16_t*   Wat  = (bf16_t*)(ws + 131072);
  unsigned* cnt  = (unsigned*)(ws + 163840);                      // 64*16 u32 = 4KB
  unsigned* list = (unsigned*)(ws + 167936);                      // 64*4096 u32 = 1MB
  bf16_t*   rec  = (bf16_t*)(ws + 1216512);                       // NBLK*48*512B = 38.4MB
  float* partial = (float*)(ws + 1216512 + (size_t)NBLK * BLK_REC * 512); // 2MB

  prep_kernel<<<64, 256, 0, stream>>>(W1, s1, W2, s2, Wa, W1t, W2t, Wat, cnt);
  main_kernel<<<NBLK, 256, 0, stream>>>(
      feature, xyz, b1, b2, W3, b3, ctr, nrm, pmn, pmx,
      W1t, W2t, Wat, cnt, list, rec, out);
  pool2_kernel<<<64 * 16, 256, 0, stream>>>(cnt, list, rec, partial);
  finalize_kernel<<<128, 128, 0, stream>>>(partial, Wm, bm, ctr, nrm, pmn, pmx, out);
}

// Round 12
// 189.140 us; speedup vs baseline: 1.1980x; 1.0101x over previous
//
#include <hip/hip_runtime.h>

#define NPTS 100000
#define P 64
#define C 128
#define NBLK 1563          // (NPTS+63)/64
#define BLK_REC 48         // rec slots per block (hit points/block: mean ~7, 48 = ~15 sigma)
#define LIST_CAP 4096      // max hit entries per plane (expected ~180)
#define CNT_STRIDE 16      // u32 stride: one 64B cache line per plane counter
                           // (device atomics serialize PER LINE: r3 1-line=+170us,
                           //  r5 4-line=+65us, r6 64-line=+13us — model confirmed)
// r9/r10 lesson: 2-tile-per-block loop induced ~41MB/dispatch spill round-trip
// (VGPR 56->64). ONE tile per block. r12: drop 2 redundant barriers (8->6):
//  - post-G2-half1 sync subsumed by epilogue barrier (next Hh write is after it)
//  - logit->mask lgS handoff is wave-local (same wave writes & reads) — no barrier;
//    logit moved before GEMMa so its global store drains under MFMA.

typedef __bf16 bf16_t;
typedef __bf16 bf16x8 __attribute__((ext_vector_type(8)));
typedef float floatx4 __attribute__((ext_vector_type(4)));

// Workspace layout (bytes):
//   [0,       65536)     W1t bf16 [256][128]   (s1 folded, transposed: [n][k])
//   [65536,  131072)     W2t bf16 [128][256]   (s2 folded, transposed)
//   [131072, 163840)     Wat bf16 [128][128]   (transposed)
//   [163840, 167936)     cnt u32 [64*16] (plane p's counter at cnt[p*16]; 64B/plane)
//   [167936, 1216512)    list u32 [64][LIST_CAP]   entry = (recRow<<1)|sel
//   [1216512, +38.4MB)   rec bf16 [NBLK*BLK_REC][256]  (a[128] | h2[128] per hit point)
//   [39628800, +2MB)     partial f32 [64][16][4][128]

__global__ __launch_bounds__(256) void prep_kernel(
    const float* __restrict__ W1, const float* __restrict__ s1,
    const float* __restrict__ W2, const float* __restrict__ s2,
    const float* __restrict__ Wa,
    bf16_t* __restrict__ W1t, bf16_t* __restrict__ W2t, bf16_t* __restrict__ Wat,
    unsigned* __restrict__ cnt)
{
  int i0 = blockIdx.x * blockDim.x + threadIdx.x;
  int stride = gridDim.x * blockDim.x;
  for (int i = i0; i < 256 * 128; i += stride) {          // W1t[n][k] = W1[k][n]*s1[n]
    int n = i >> 7, k = i & 127;
    W1t[i] = (bf16_t)(W1[k * 256 + n] * s1[n]);
  }
  for (int i = i0; i < 128 * 256; i += stride) {          // W2t[n][k] = W2[k][n]*s2[n]
    int n = i >> 8, k = i & 255;
    W2t[i] = (bf16_t)(W2[k * 128 + n] * s2[n]);
  }
  for (int i = i0; i < 128 * 128; i += stride) {          // Wat[n][k] = Wa[k][n]
    int n = i >> 7, k = i & 127;
    Wat[i] = (bf16_t)(Wa[k * 128 + n]);
  }
  if (i0 < 64 * CNT_STRIDE) cnt[i0] = 0;                  // zero padded counters
}

// Fused: feature -> h -> h2 -> (logit, a=h2@Wa) -> plane-mask sparse emit.
// LDS 36.4KB: h computed in TWO 128-col halves staged in Hh[64][136], each
// immediately consumed into the persistent GEMM2 accumulator. 6 barriers/tile.
__global__ __launch_bounds__(256, 4) void main_kernel(
    const float* __restrict__ feature, const float* __restrict__ xyz,
    const float* __restrict__ b1, const float* __restrict__ b2,
    const float* __restrict__ W3, const float* __restrict__ b3,
    const float* __restrict__ ctr, const float* __restrict__ nrm,
    const float* __restrict__ pmn, const float* __restrict__ pmx,
    const bf16_t* __restrict__ W1t, const bf16_t* __restrict__ W2t,
    const bf16_t* __restrict__ Wat,
    unsigned* __restrict__ cnt, unsigned* __restrict__ list,
    bf16_t* __restrict__ rec, float* __restrict__ out_logit)
{
  // LDS: A1 bf16[64][136] (feature tile; later h2)          @0      17408
  //      Hh bf16[64][136] (h-half; later aB = a output)     @17408  17408
  //      w3S f32[128] @34816 | xyzS f32[192] @35328 | lgS f32[64] @36096 | blkCnt @36352
  __shared__ __align__(16) char smem[36368];
  bf16_t* A1   = (bf16_t*)smem;
  bf16_t* Hh   = (bf16_t*)(smem + 17408);
  bf16_t* aB   = (bf16_t*)(smem + 17408);          // overlays Hh after GEMM2
  float*  w3S  = (float*)(smem + 34816);
  float*  xyzS = (float*)(smem + 35328);
  float*  lgS  = (float*)(smem + 36096);
  unsigned* blkCnt = (unsigned*)(smem + 36352);

  const int tid  = threadIdx.x;
  const int wave = tid >> 6, lane = tid & 63;
  const int quad = lane >> 4, l16 = lane & 15;
  const int m0 = blockIdx.x * 64;

  if (tid < 128) w3S[tid] = W3[tid];
  if (tid < 192) {                                  // stage xyz tile (64 pts x 3)
    int gi = m0 * 3 + tid;
    xyzS[tid] = (gi < NPTS * 3) ? xyz[gi] : 0.f;
  }
  if (tid == 0) *blkCnt = 0;

  // ---- stage feature tile (fp32 -> bf16) ----
  for (int i = tid; i < 64 * 32; i += 256) {   // 32 float4 per row
    int r = i >> 5, c4 = i & 31;
    float4 v = make_float4(0.f, 0.f, 0.f, 0.f);
    if (m0 + r < NPTS) v = *(const float4*)(feature + (size_t)(m0 + r) * C + c4 * 4);
    bf16_t* dst = A1 + r * 136 + c4 * 4;
    dst[0] = (bf16_t)v.x; dst[1] = (bf16_t)v.y; dst[2] = (bf16_t)v.z; dst[3] = (bf16_t)v.w;
  }
  __syncthreads();                                  // B1: staging done

  const floatx4 zero4 = {0.f, 0.f, 0.f, 0.f};

  // ---- GEMM1+GEMM2 fused over two 128-col halves of h ----
  // acc2 accumulates h2 = relu(h @ W2' + b2) across both halves' k-ranges.
  floatx4 acc2[4][2];
#pragma unroll
  for (int mt = 0; mt < 4; ++mt) { acc2[mt][0] = zero4; acc2[mt][1] = zero4; }

#pragma unroll
  for (int half = 0; half < 2; ++half) {
    // GEMM1 half: h[:, half*128 + (0..128)] = relu(A1 @ W1t-half + b1)
    floatx4 acc1[4][2];
#pragma unroll
    for (int mt = 0; mt < 4; ++mt) { acc1[mt][0] = zero4; acc1[mt][1] = zero4; }
#pragma unroll
    for (int kt = 0; kt < 4; ++kt) {
      bf16x8 af[4], bfr[2];
#pragma unroll
      for (int mt = 0; mt < 4; ++mt)
        af[mt] = *(const bf16x8*)(A1 + (mt * 16 + l16) * 136 + kt * 32 + quad * 8);
#pragma unroll
      for (int nt = 0; nt < 2; ++nt)
        bfr[nt] = *(const bf16x8*)(W1t + (size_t)(half * 128 + wave * 32 + nt * 16 + l16) * 128 + kt * 32 + quad * 8);
#pragma unroll
      for (int mt = 0; mt < 4; ++mt)
#pragma unroll
        for (int nt = 0; nt < 2; ++nt)
          acc1[mt][nt] = __builtin_amdgcn_mfma_f32_16x16x32_bf16(af[mt], bfr[nt], acc1[mt][nt], 0, 0, 0);
    }
#pragma unroll
    for (int nt = 0; nt < 2; ++nt) {
      int hcol = wave * 32 + nt * 16 + l16;
      float bias = b1[half * 128 + hcol];
#pragma unroll
      for (int mt = 0; mt < 4; ++mt)
#pragma unroll
        for (int r = 0; r < 4; ++r) {
          float hv = fmaxf(acc1[mt][nt][r] + bias, 0.f);
          Hh[(mt * 16 + quad * 4 + r) * 136 + hcol] = (bf16_t)hv;
        }
    }
    __syncthreads();     // B2/B4: Hh half ready

    // GEMM2 partial: accumulate over this half's k-range
#pragma unroll
    for (int kt = 0; kt < 4; ++kt) {
      bf16x8 af[4], bfr[2];
#pragma unroll
      for (int mt = 0; mt < 4; ++mt)
        af[mt] = *(const bf16x8*)(Hh + (mt * 16 + l16) * 136 + kt * 32 + quad * 8);
#pragma unroll
      for (int nt = 0; nt < 2; ++nt)
        bfr[nt] = *(const bf16x8*)(W2t + (size_t)(wave * 32 + nt * 16 + l16) * 256 + half * 128 + kt * 32 + quad * 8);
#pragma unroll
      for (int mt = 0; mt < 4; ++mt)
#pragma unroll
        for (int nt = 0; nt < 2; ++nt)
          acc2[mt][nt] = __builtin_amdgcn_mfma_f32_16x16x32_bf16(af[mt], bfr[nt], acc2[mt][nt], 0, 0, 0);
    }
    if (half == 0)
      __syncthreads();   // B3: Hh half0 reads done (half1 G1 overwrites Hh)
    // half==1: NO barrier — next Hh-region write (GEMMa's aB) is after B5,
    // which already orders it after these reads. (r12 barrier elision #1)
  }

  // ---- GEMM2 epilogue: h2 -> bf16 into A1 (feature no longer needed) ----
  // A1's last reads (G1-half1) precede B4; safe to overwrite here.
#pragma unroll
  for (int nt = 0; nt < 2; ++nt) {
    int col = wave * 32 + nt * 16 + l16;
    float bias = b2[col];
#pragma unroll
    for (int mt = 0; mt < 4; ++mt)
#pragma unroll
      for (int r = 0; r < 4; ++r) {
        float hv = fmaxf(acc2[mt][nt][r] + bias, 0.f);
        A1[(mt * 16 + quad * 4 + r) * 136 + col] = (bf16_t)hv;
      }
  }
  __syncthreads();   // B5: A1 now h2, visible to all

  // ---- logit (moved before GEMMa; lgS handoff is wave-local, no barrier) ----
  {
    const int m = tid >> 2, g = tid & 3, c0g = g * 32;
    const int mg = m0 + m;
    float lsum = 0.f;
#pragma unroll 8
    for (int c = 0; c < 32; ++c)
      lsum += (float)A1[m * 136 + c0g + c] * w3S[c0g + c];
    lsum += __shfl_xor(lsum, 1);
    lsum += __shfl_xor(lsum, 2);
    if (g == 0) {
      float lg = lsum + b3[0];
      lgS[m] = lg;                                  // read by SAME wave in mask phase
      if (mg < NPTS) out_logit[mg] = lg;            // store drains under GEMMa
    }
  }

  // ---- GEMMa: a[64][128] = h2 @ Wa -> bf16 into aB (overlays Hh) ----
  {
    floatx4 acca[4][2];
#pragma unroll
    for (int mt = 0; mt < 4; ++mt) { acca[mt][0] = zero4; acca[mt][1] = zero4; }
#pragma unroll
    for (int kt = 0; kt < 4; ++kt) {
      bf16x8 af[4], bfr[2];
#pragma unroll
      for (int mt = 0; mt < 4; ++mt)
        af[mt] = *(const bf16x8*)(A1 + (mt * 16 + l16) * 136 + kt * 32 + quad * 8);
#pragma unroll
      for (int nt = 0; nt < 2; ++nt)
        bfr[nt] = *(const bf16x8*)(Wat + (size_t)(wave * 32 + nt * 16 + l16) * 128 + kt * 32 + quad * 8);
#pragma unroll
      for (int mt = 0; mt < 4; ++mt)
#pragma unroll
        for (int nt = 0; nt < 2; ++nt)
          acca[mt][nt] = __builtin_amdgcn_mfma_f32_16x16x32_bf16(af[mt], bfr[nt], acca[mt][nt], 0, 0, 0);
    }
#pragma unroll
    for (int nt = 0; nt < 2; ++nt) {
      int col = wave * 32 + nt * 16 + l16;
#pragma unroll
      for (int mt = 0; mt < 4; ++mt)
#pragma unroll
        for (int r = 0; r < 4; ++r)
          aB[(mt * 16 + quad * 4 + r) * 136 + col] = (bf16_t)acca[mt][nt][r];
    }
  }
  __syncthreads();   // B6: aB visible to all

  // ---- fused mask phase: lane = plane (P==64==wave width); sparse emit ----
  {
    const float nx = nrm[lane * 3], ny = nrm[lane * 3 + 1], nz = nrm[lane * 3 + 2];
    const float offsP = ctr[lane * 3] * nx + ctr[lane * 3 + 1] * ny + ctr[lane * 3 + 2] * nz;
    const float mnx = pmn[lane * 3], mny = pmn[lane * 3 + 1];
    const float mxx = pmx[lane * 3], mxy = pmx[lane * 3 + 1];

    // wave w owns points [w*16, w*16+16)
    for (int s = 0; s < 16; ++s) {
      const int pt = wave * 16 + s;
      const bool valid = (m0 + pt) < NPTS;
      const float x = xyzS[pt * 3], y = xyzS[pt * 3 + 1], z = xyzS[pt * 3 + 2];
      const float proj = x * nx + y * ny + z * nz;
      const bool hit = valid && (fabsf(proj - offsP) < 0.1f) &&
                       (x >= mnx) && (x < mxx) && (y >= mny) && (y < mxy);
      unsigned long long mball = __ballot(hit);
      if (!mball) continue;                         // wave-uniform skip

      unsigned slot = 0;                            // block-local rec slot (LDS atomic)
      if (lane == 0) slot = atomicAdd(blkCnt, 1u);
      slot = (unsigned)__shfl((int)slot, 0);
      if (slot >= BLK_REC) continue;                // ~15-sigma overflow guard

      const unsigned ridx = (unsigned)blockIdx.x * BLK_REC + slot;
      const int sel = (lgS[pt] > 0.f) ? 0 : 1;      // on=0, off=1 (wave-local lgS)
      const unsigned ap = ((const unsigned*)(aB + pt * 136))[lane];
      const unsigned hp = ((const unsigned*)(A1 + pt * 136))[lane];
      unsigned* dst = (unsigned*)(rec + (size_t)ridx * 256);
      dst[lane]      = ap;                           // a row  (bf16 pairs)
      dst[64 + lane] = hp;                           // h2 row
      if (hit) {                                     // hitting lane -> its plane's list
        unsigned idx = atomicAdd(&cnt[lane * CNT_STRIDE], 1u);  // private 64B line
        if (idx < LIST_CAP)
          list[lane * LIST_CAP + idx] = (ridx << 1) | (unsigned)sel;
      }
    }
  }
}

// Gather: 64 planes x 16 chunks (1024 blocks — r7's 64-block fusion was
// latency-dead at 1 wave/CU). Register accum, LDS reduce, write partials.
__global__ __launch_bounds__(256) void pool2_kernel(
    const unsigned* __restrict__ cnt, const unsigned* __restrict__ list,
    const bf16_t* __restrict__ rec, float* __restrict__ partial)
{
  const int plane = blockIdx.x >> 4;
  const int chunk = blockIdx.x & 15;
  const int tid = threadIdx.x, wave = tid >> 6, lane = tid & 63;

  __shared__ float accS[4][128];   // num_on, den_on, num_off, den_off
  for (int i = tid; i < 512; i += 256) ((float*)accS)[i] = 0.f;
  __syncthreads();

  unsigned n = cnt[plane * CNT_STRIDE];
  if (n > LIST_CAP) n = LIST_CAP;
  const unsigned* lp = list + plane * LIST_CAP;

  float nOn0 = 0, nOn1 = 0, dOn0 = 0, dOn1 = 0;
  float nOf0 = 0, nOf1 = 0, dOf0 = 0, dOf1 = 0;

  for (unsigned e = (unsigned)(chunk * 4 + wave); e < n; e += 64) {
    const unsigned ent = lp[e];                     // wave-uniform load
    const unsigned row = ent >> 1;
    const unsigned* r32 = (const unsigned*)(rec + (size_t)row * 256);
    const unsigned ap = r32[lane];
    const unsigned hp = r32[64 + lane];
    const float a0 = __uint_as_float(ap << 16);
    const float a1 = __uint_as_float(ap & 0xffff0000u);
    const float h0 = __uint_as_float(hp << 16);
    const float h1 = __uint_as_float(hp & 0xffff0000u);
    const float e0 = __expf(a0), e1 = __expf(a1);
    if (!(ent & 1)) { nOn0 += e0 * h0; nOn1 += e1 * h1; dOn0 += e0; dOn1 += e1; }
    else            { nOf0 += e0 * h0; nOf1 += e1 * h1; dOf0 += e0; dOf1 += e1; }
  }

  atomicAdd(&accS[0][lane * 2],     nOn0);
  atomicAdd(&accS[0][lane * 2 + 1], nOn1);
  atomicAdd(&accS[1][lane * 2],     dOn0);
  atomicAdd(&accS[1][lane * 2 + 1], dOn1);
  atomicAdd(&accS[2][lane * 2],     nOf0);
  atomicAdd(&accS[2][lane * 2 + 1], nOf1);
  atomicAdd(&accS[3][lane * 2],     dOf0);
  atomicAdd(&accS[3][lane * 2 + 1], dOf1);
  __syncthreads();

  float* dst = partial + (size_t)blockIdx.x * 512;
  for (int i = tid; i < 512; i += 256) dst[i] = ((float*)accS)[i];
}

// Finalize: sum partials over chunks, agg = num/(den+1e-9), relu(agg@Wm+bm), ori.
__global__ __launch_bounds__(128) void finalize_kernel(
    const float* __restrict__ partial,
    const float* __restrict__ Wm, const float* __restrict__ bm,
    const float* __restrict__ ctr, const float* __restrict__ nrm,
    const float* __restrict__ pmn, const float* __restrict__ pmx,
    float* __restrict__ out)
{
  int sel = blockIdx.x >> 6, p = blockIdx.x & 63;
  int j = threadIdx.x;
  float num = 0.f, den = 0.f;
  const float* bp = partial + (size_t)p * 16 * 512 + sel * 2 * 128;
#pragma unroll
  for (int k = 0; k < 16; ++k) {
    num += bp[k * 512 + j];
    den += bp[k * 512 + 128 + j];
  }
  __shared__ float aggS[128];
  aggS[j] = num / (den + 1e-9f);
  __syncthreads();
  float s = bm[j];
#pragma unroll 4
  for (int c = 0; c < C; ++c) s += aggS[c] * Wm[c * C + j];
  s = fmaxf(s, 0.f);
  float* dst = out + NPTS + sel * (P * 140) + p * 140;
  dst[j] = s;
  if (j < 12) {
    float v;
    if (j < 3)      v = ctr[p * 3 + j];
    else if (j < 6) v = nrm[p * 3 + j - 3];
    else if (j < 9) v = pmn[p * 3 + j - 6];
    else            v = pmx[p * 3 + j - 9];
    dst[C + j] = v;
  }
}

extern "C" void kernel_launch(void* const* d_in, const int* in_sizes, int n_in,
                              void* d_out, int out_size, void* d_ws, size_t ws_size,
                              hipStream_t stream)
{
  const float* feature = (const float*)d_in[0];
  const float* xyz     = (const float*)d_in[1];
  const float* ctr     = (const float*)d_in[2];
  const float* nrm     = (const float*)d_in[3];
  const float* pmn     = (const float*)d_in[4];
  const float* pmx     = (const float*)d_in[5];
  const float* W1      = (const float*)d_in[6];
  const float* s1      = (const float*)d_in[7];
  const float* b1      = (const float*)d_in[8];
  const float* W2      = (const float*)d_in[9];
  const float* s2      = (const float*)d_in[10];
  const float* b2      = (const float*)d_in[11];
  const float* W3      = (const float*)d_in[12];
  const float* b3      = (const float*)d_in[13];
  const float* Wa      = (const float*)d_in[14];
  const float* Wm      = (const float*)d_in[15];
  const float* bm      = (const float*)d_in[16];
  float* out = (float*)d_out;

  char* ws = (char*)d_ws;
  bf16_t*   W1t  = (bf16_t*)(ws);
  bf16_t*   W2t  = (bf16_t*)(ws + 65536);
  bf16_t*   Wat  = (bf16_t*)(ws + 131072);
  unsigned* cnt  = (unsigned*)(ws + 163840);                      // 64*16 u32 = 4KB
  unsigned* list = (unsigned*)(ws + 167936);                      // 64*4096 u32 = 1MB
  bf16_t*   rec  = (bf16_t*)(ws + 1216512);                       // NBLK*48*512B = 38.4MB
  float* partial = (float*)(ws + 1216512 + (size_t)NBLK * BLK_REC * 512); // 2MB

  prep_kernel<<<64, 256, 0, stream>>>(W1, s1, W2, s2, Wa, W1t, W2t, Wat, cnt);
  main_kernel<<<NBLK, 256, 0, stream>>>(
      feature, xyz, b1, b2, W3, b3, ctr, nrm, pmn, pmx,
      W1t, W2t, Wat, cnt, list, rec, out);
  pool2_kernel<<<64 * 16, 256, 0, stream>>>(cnt, list, rec, partial);
  finalize_kernel<<<128, 128, 0, stream>>>(partial, Wm, bm, ctr, nrm, pmn, pmx, out);
}